// Round 9
// baseline (1152.350 us; speedup 1.0000x reference)
//
#include <hip/hip_runtime.h>
#include <math.h>
#include <stdint.h>

#define LAT 64
#define SLICE 16384
#define BIN_CHUNK 1024

static inline int cdiv(int a, int b) { return (a + b - 1) / b; }

// ---------------- scans ----------------
__global__ void k_scan1(const int* __restrict__ cnt, int N, int* __restrict__ out, int* __restrict__ blk_sums) {
    __shared__ int sdata[256];
    int t = threadIdx.x, b = blockIdx.x;
    int base = b * 1024 + t * 4;
    int v[4];
    int s = 0;
#pragma unroll
    for (int u = 0; u < 4; u++) { int i = base + u; v[u] = (i < N) ? cnt[i] : 0; s += v[u]; }
    sdata[t] = s; __syncthreads();
    for (int off = 1; off < 256; off <<= 1) {
        int x = (t >= off) ? sdata[t - off] : 0;
        __syncthreads();
        sdata[t] += x;
        __syncthreads();
    }
    int run = sdata[t] - s;
#pragma unroll
    for (int u = 0; u < 4; u++) { int i = base + u; if (i < N) out[i] = run; run += v[u]; }
    if (t == 255) blk_sums[b] = sdata[255];
}

__global__ void k_scan2(int* __restrict__ blk_sums, int NB) {
    __shared__ int sdata[256];
    int t = threadIdx.x;
    int v = (t < NB) ? blk_sums[t] : 0;
    sdata[t] = v; __syncthreads();
    for (int off = 1; off < 256; off <<= 1) {
        int x = (t >= off) ? sdata[t - off] : 0;
        __syncthreads();
        sdata[t] += x;
        __syncthreads();
    }
    if (t < NB) blk_sums[t] = sdata[t] - v;  // exclusive
}

__global__ void k_scan3(int* __restrict__ row_ptr, const int* __restrict__ blk_offs, int N, int ET) {
    int t = threadIdx.x, b = blockIdx.x;
    int base = b * 1024 + t * 4;
    int off = blk_offs[b];
#pragma unroll
    for (int u = 0; u < 4; u++) { int i = base + u; if (i < N) row_ptr[i] += off; }
    if (b == 0 && t == 0) row_ptr[N] = ET;
}

// ---------------- fused layer-0 transform + binA ----------------
__global__ __launch_bounds__(256) void k_l0(
        const float* __restrict__ ueo, const float* __restrict__ ieo,
        const float* __restrict__ uet, const float* __restrict__ iet, int NU,
        const float* __restrict__ Wo, const float* __restrict__ Wt,
        const float* __restrict__ atso, const float* __restrict__ atdo,
        const float* __restrict__ atst, const float* __restrict__ atdt,
        float* __restrict__ h2, float* __restrict__ asp, float* __restrict__ adp, int N,
        int gemmGrid, int binGrid,
        const int* __restrict__ src_arr, const int* __restrict__ dst_arr,
        int E, int ET, int rsz, int bcap,
        int2* __restrict__ buckets, int* __restrict__ gcur, int* __restrict__ cnt) {
    __shared__ float sW[64 * 64];
    __shared__ float sX[128 * 65];
    __shared__ float sAs[64], sAd[64];
    int t = threadIdx.x;

    if ((int)blockIdx.x >= gemmGrid) {
        // ---- binA body ----
        int* lcnt = (int*)sW;
        int* lbase = (int*)sW + 8;
        int bb = blockIdx.x - gemmGrid;
        for (int base = bb * BIN_CHUNK; base < ET; base += binGrid * BIN_CHUNK) {
            if (t < 8) lcnt[t] = 0;
            __syncthreads();
            int s[4], d[4], r[4], lofs[4];
            int nval = 0;
            if (base + BIN_CHUNK <= E) {
                int4 s4 = ((const int4*)(src_arr + base))[t];
                int4 d4 = ((const int4*)(dst_arr + base))[t];
                s[0] = s4.x; s[1] = s4.y; s[2] = s4.z; s[3] = s4.w;
                d[0] = d4.x; d[1] = d4.y; d[2] = d4.z; d[3] = d4.w;
                nval = 4;
            } else {
                for (int k = 0; k < 4; k++) {
                    int e = base + t * 4 + k;
                    if (e < ET) {
                        if (e < E) { s[nval] = src_arr[e]; d[nval] = dst_arr[e]; }
                        else { s[nval] = e - E; d[nval] = e - E; }
                        nval++;
                    }
                }
            }
            for (int k = 0; k < nval; k++) {
                r[k] = d[k] / rsz;
                lofs[k] = atomicAdd(&lcnt[r[k]], 1);
                atomicAdd(&cnt[d[k]], 1);
            }
            __syncthreads();
            if (t < 8) lbase[t] = atomicAdd(&gcur[t], lcnt[t]);
            __syncthreads();
            for (int k = 0; k < nval; k++) {
                buckets[(size_t)r[k] * bcap + lbase[r[k]] + lofs[k]] = make_int2(s[k], d[k]);
            }
            __syncthreads();
        }
        return;
    }

    // ---- layer-0 gemm body ----
    int enc = blockIdx.x & 1;
    int bb = blockIdx.x >> 1;
    const float* ue = enc ? uet : ueo;
    const float* ie = enc ? iet : ieo;
    const float* W = enc ? Wt : Wo;
    const float* att_s = enc ? atst : atso;
    const float* att_d = enc ? atdt : atdo;
    float* h2e = h2 + enc * 64;
    int row0 = bb * 128;
    {
        const float4* Wv = (const float4*)W;
        float4* sWv = (float4*)sW;
#pragma unroll
        for (int u = 0; u < 4; u++) sWv[t + 256 * u] = Wv[t + 256 * u];
    }
    if (t < 64) { sAs[t] = att_s[t]; sAd[t] = att_d[t]; }
    {
#pragma unroll
        for (int u = 0; u < 8; u++) {
            int idx = t + 256 * u;
            int r = idx >> 4, c4 = idx & 15;
            int grow = row0 + r;
            float4 v = make_float4(0.f, 0.f, 0.f, 0.f);
            if (grow < N) {
                const float* base = (grow < NU) ? ue + (size_t)grow * 64 : ie + (size_t)(grow - NU) * 64;
                v = ((const float4*)base)[c4];
            }
            int cc = c4 * 4;
            sX[r * 65 + cc] = v.x; sX[r * 65 + cc + 1] = v.y; sX[r * 65 + cc + 2] = v.z; sX[r * 65 + cc + 3] = v.w;
        }
    }
    __syncthreads();
    int rl = t >> 2;
    int g = t & 3;
    int c0 = g * 16;
    int rA = rl * 2, rB = rA + 1;
    float accA[16], accB[16];
#pragma unroll
    for (int j = 0; j < 16; j++) { accA[j] = 0.f; accB[j] = 0.f; }
    for (int k = 0; k < 64; k++) {
        float xa = sX[rA * 65 + k];
        float xb = sX[rB * 65 + k];
        const float4* wr = (const float4*)&sW[k * 64 + c0];
        float4 w0 = wr[0], w1 = wr[1], w2 = wr[2], w3 = wr[3];
        accA[0] += xa * w0.x; accA[1] += xa * w0.y; accA[2] += xa * w0.z; accA[3] += xa * w0.w;
        accA[4] += xa * w1.x; accA[5] += xa * w1.y; accA[6] += xa * w1.z; accA[7] += xa * w1.w;
        accA[8] += xa * w2.x; accA[9] += xa * w2.y; accA[10] += xa * w2.z; accA[11] += xa * w2.w;
        accA[12] += xa * w3.x; accA[13] += xa * w3.y; accA[14] += xa * w3.z; accA[15] += xa * w3.w;
        accB[0] += xb * w0.x; accB[1] += xb * w0.y; accB[2] += xb * w0.z; accB[3] += xb * w0.w;
        accB[4] += xb * w1.x; accB[5] += xb * w1.y; accB[6] += xb * w1.z; accB[7] += xb * w1.w;
        accB[8] += xb * w2.x; accB[9] += xb * w2.y; accB[10] += xb * w2.z; accB[11] += xb * w2.w;
        accB[12] += xb * w3.x; accB[13] += xb * w3.y; accB[14] += xb * w3.z; accB[15] += xb * w3.w;
    }
    float sA = 0.f, dA = 0.f, sB = 0.f, dB = 0.f;
#pragma unroll
    for (int j = 0; j < 16; j++) {
        sA += accA[j] * sAs[c0 + j]; dA += accA[j] * sAd[c0 + j];
        sB += accB[j] * sAs[c0 + j]; dB += accB[j] * sAd[c0 + j];
    }
    sA += __shfl_xor(sA, 1); sA += __shfl_xor(sA, 2);
    dA += __shfl_xor(dA, 1); dA += __shfl_xor(dA, 2);
    sB += __shfl_xor(sB, 1); sB += __shfl_xor(sB, 2);
    dB += __shfl_xor(dB, 1); dB += __shfl_xor(dB, 2);
    int rowA = row0 + rA, rowB = row0 + rB;
    if (rowA < N) {
        if (g == 0) { asp[(size_t)rowA * 2 + enc] = sA; adp[(size_t)rowA * 2 + enc] = dA; }
        float4* hv = (float4*)&h2e[(size_t)rowA * 128 + c0];
        hv[0] = make_float4(accA[0], accA[1], accA[2], accA[3]);
        hv[1] = make_float4(accA[4], accA[5], accA[6], accA[7]);
        hv[2] = make_float4(accA[8], accA[9], accA[10], accA[11]);
        hv[3] = make_float4(accA[12], accA[13], accA[14], accA[15]);
    }
    if (rowB < N) {
        if (g == 0) { asp[(size_t)rowB * 2 + enc] = sB; adp[(size_t)rowB * 2 + enc] = dB; }
        float4* hv = (float4*)&h2e[(size_t)rowB * 128 + c0];
        hv[0] = make_float4(accB[0], accB[1], accB[2], accB[3]);
        hv[1] = make_float4(accB[4], accB[5], accB[6], accB[7]);
        hv[2] = make_float4(accB[8], accB[9], accB[10], accB[11]);
        hv[3] = make_float4(accB[12], accB[13], accB[14], accB[15]);
    }
}

// Phase B: XCD-affine scatter from buckets.
__global__ __launch_bounds__(256) void k_binB(const int2* __restrict__ buckets, int bcap,
                                              const int* __restrict__ gcur,
                                              const int* __restrict__ row_ptr, int* __restrict__ cnt,
                                              int* __restrict__ csr_src) {
    int r = blockIdx.x & 7;
    int nb = blockIdx.x >> 3;
    int stride = (gridDim.x >> 3) * 256;
    int total = gcur[r];
    const int* bp = (const int*)(buckets + (size_t)r * bcap);
    for (int i = nb * 256 + threadIdx.x; i < total; i += stride) {
        int s = __builtin_nontemporal_load(bp + 2 * i);
        int d = __builtin_nontemporal_load(bp + 2 * i + 1);
        int pos = atomicAdd(&cnt[d], 1);
        csr_src[row_ptr[d] + pos] = s;
    }
}

// ---------------- fused agg(l) + transform(l+1) ----------------
// One dst per wave, one-shot blocks (no grid-stride); blocks specialize by
// encoder (enc = blockIdx&1) -> LDS = one 64x64 W (16.6KB), regs low, high
// occupancy. Since layers have no nonlinearity, x is never materialized:
// h_out = (agg + bias) @ Wn, scores for layer l+1 from h_out.
__global__ __launch_bounds__(256) void k_fagg(const float* __restrict__ h2_in,
        const int* __restrict__ row_ptr, const int* __restrict__ csr_src,
        const float* __restrict__ asv_in, const float* __restrict__ adv_in,   // strided-2
        const float* __restrict__ bias_o, const float* __restrict__ bias_t,   // layer-l bias
        const float* __restrict__ Wn_o, const float* __restrict__ Wn_t,       // layer-(l+1) W
        const float* __restrict__ atsn_o, const float* __restrict__ atdn_o,
        const float* __restrict__ atsn_t, const float* __restrict__ atdn_t,
        float* __restrict__ h2_out, float* __restrict__ asv_out, float* __restrict__ adv_out,
        int N) {
    __shared__ float sW[64 * 65];    // transposed: sW[c*65+k] = Wn[k][c]
    int enc = blockIdx.x & 1;
    int bb = blockIdx.x >> 1;
    int t = threadIdx.x;
    const float* Wn = enc ? Wn_t : Wn_o;
#pragma unroll
    for (int u = 0; u < 16; u++) {
        int i = u * 256 + t;
        int k = i >> 6, c = i & 63;
        sW[c * 65 + k] = Wn[i];
    }
    int wid = t >> 6, lane = t & 63;
    int d = bb * 4 + wid;
    float attS = (enc ? atsn_t : atsn_o)[lane];
    float attD = (enc ? atdn_t : atdn_o)[lane];
    int c4 = lane & 15, sub = lane >> 4;
    float4 bias4 = ((const float4*)(enc ? bias_t : bias_o))[c4];
    __syncthreads();
    if (d >= N) return;

    int s0 = row_ptr[d], s1 = row_ptr[d + 1];
    float advv = adv_in[(size_t)d * 2 + enc];
    int j0 = s0 + lane;
    int sv0 = 0; float e0 = -1e30f;
    if (j0 < s1) {
        sv0 = csr_src[j0];
        float e = asv_in[(size_t)sv0 * 2 + enc] + advv;
        e0 = (e > 0.f) ? e : 0.2f * e;
    }
    float m = e0;
    for (int j = j0 + 64; j < s1; j += 64) {   // rare: deg > 64
        float e = asv_in[(size_t)csr_src[j] * 2 + enc] + advv;
        e = (e > 0.f) ? e : 0.2f * e;
        m = fmaxf(m, e);
    }
#pragma unroll
    for (int o = 32; o; o >>= 1) m = fmaxf(m, __shfl_xor(m, o));
    float ex0 = (j0 < s1) ? expf(e0 - m) : 0.f;
    float sum = ex0;
    for (int j = j0 + 64; j < s1; j += 64) {   // rare
        float e = asv_in[(size_t)csr_src[j] * 2 + enc] + advv;
        e = (e > 0.f) ? e : 0.2f * e;
        sum += expf(e - m);
    }
#pragma unroll
    for (int o = 32; o; o >>= 1) sum += __shfl_xor(sum, o);
    float inv = 1.f / sum;
    ex0 *= inv;
    float4 acc = make_float4(0.f, 0.f, 0.f, 0.f);
    for (int cb = s0; cb < s1; cb += 64) {
        int sv; float ex;
        if (cb == s0) { sv = sv0; ex = ex0; }
        else {                                 // rare: deg > 64
            int jj = cb + lane; sv = 0; ex = 0.f;
            if (jj < s1) {
                sv = csr_src[jj];
                float e = asv_in[(size_t)sv * 2 + enc] + advv;
                e = (e > 0.f) ? e : 0.2f * e;
                ex = expf(e - m) * inv;
            }
        }
        int c = s1 - cb; if (c > 64) c = 64;
        int q = 0;
        for (; q + 8 <= c; q += 8) {           // 2 groups in flight
            int ilA = q + sub, ilB = q + 4 + sub;
            int sA = __shfl(sv, ilA), sB = __shfl(sv, ilB);
            float wA = __shfl(ex, ilA), wB = __shfl(ex, ilB);
            float4 hA = *(const float4*)&h2_in[(size_t)sA * 128 + enc * 64 + (c4 << 2)];
            float4 hB = *(const float4*)&h2_in[(size_t)sB * 128 + enc * 64 + (c4 << 2)];
            acc.x += wA * hA.x; acc.y += wA * hA.y; acc.z += wA * hA.z; acc.w += wA * hA.w;
            acc.x += wB * hB.x; acc.y += wB * hB.y; acc.z += wB * hB.z; acc.w += wB * hB.w;
        }
        for (; q < c; q += 4) {
            int il = q + sub;
            int s = __shfl(sv, il);
            float w = __shfl(ex, il);
            float4 hv = *(const float4*)&h2_in[(size_t)s * 128 + enc * 64 + (c4 << 2)];
            acc.x += w * hv.x; acc.y += w * hv.y; acc.z += w * hv.z; acc.w += w * hv.w;
        }
    }
#pragma unroll
    for (int o = 16; o <= 32; o <<= 1) {
        acc.x += __shfl_xor(acc.x, o); acc.y += __shfl_xor(acc.y, o);
        acc.z += __shfl_xor(acc.z, o); acc.w += __shfl_xor(acc.w, o);
    }
    // x row quad (replicated across the 4 sub-groups) + bias
    float4 xr;
    xr.x = acc.x + bias4.x; xr.y = acc.y + bias4.y;
    xr.z = acc.z + bias4.z; xr.w = acc.w + bias4.w;
    // transform: lane owns output column `lane`
    float hacc = 0.f;
#pragma unroll
    for (int k4 = 0; k4 < 16; k4++) {
        const float4 wv = *(const float4*)&sW[lane * 65 + k4 * 4];
        hacc += __shfl(xr.x, k4) * wv.x + __shfl(xr.y, k4) * wv.y +
                __shfl(xr.z, k4) * wv.z + __shfl(xr.w, k4) * wv.w;
    }
    float so = hacc * attS, sd = hacc * attD;
#pragma unroll
    for (int o = 32; o; o >>= 1) { so += __shfl_xor(so, o); sd += __shfl_xor(sd, o); }
    h2_out[(size_t)d * 128 + enc * 64 + lane] = hacc;
    if (lane == 0) {
        asv_out[(size_t)d * 2 + enc] = so;
        adv_out[(size_t)d * 2 + enc] = sd;
    }
}

// ---------------- combined-encoder softmax-aggregate (sel mode, final layer) ----------------
__global__ __launch_bounds__(256) void k_agg2(const float* __restrict__ h2,
                                              const int* __restrict__ row_ptr, const int* __restrict__ csr_src,
                                              const float2* __restrict__ asv, const float2* __restrict__ adv,
                                              const float* __restrict__ bias_o, const float* __restrict__ bias_t,
                                              float* __restrict__ xo, float* __restrict__ xt, int N,
                                              const int* __restrict__ selu, const int* __restrict__ seli,
                                              int nSel, int nSelU, int NU,
                                              float* __restrict__ selxo, float* __restrict__ outT_u,
                                              float* __restrict__ outT_i) {
    int wid = threadIdx.x >> 6, lane = threadIdx.x & 63;
    int r = blockIdx.x * 4 + wid;
    int d;
    float *po, *pt;
    if (selu) {
        if (r >= nSel) return;
        if (r < nSelU) { d = selu[r]; pt = outT_u + (size_t)r * 64; }
        else { int rr = r - nSelU; d = seli[rr] + NU; pt = outT_i + (size_t)rr * 64; }
        po = selxo + (size_t)r * 64;
    } else {
        if (r >= N) return;
        d = r;
        po = xo + (size_t)d * 64;
        pt = xt + (size_t)d * 64;
    }
    int s0 = row_ptr[d], s1 = row_ptr[d + 1];
    float2 advv = adv[d];
    int j0 = s0 + lane;
    int sv0 = 0; float eo0 = -1e30f, et0 = -1e30f;
    if (j0 < s1) {
        sv0 = csr_src[j0];
        float2 a2 = asv[sv0];
        float eo = a2.x + advv.x; eo0 = (eo > 0.f) ? eo : 0.2f * eo;
        float et = a2.y + advv.y; et0 = (et > 0.f) ? et : 0.2f * et;
    }
    float mo = eo0, mt = et0;
    for (int j = j0 + 64; j < s1; j += 64) {
        float2 a2 = asv[csr_src[j]];
        float eo = a2.x + advv.x; eo = (eo > 0.f) ? eo : 0.2f * eo; mo = fmaxf(mo, eo);
        float et = a2.y + advv.y; et = (et > 0.f) ? et : 0.2f * et; mt = fmaxf(mt, et);
    }
#pragma unroll
    for (int o = 32; o; o >>= 1) { mo = fmaxf(mo, __shfl_xor(mo, o)); mt = fmaxf(mt, __shfl_xor(mt, o)); }
    float exo0 = (j0 < s1) ? expf(eo0 - mo) : 0.f;
    float ext0 = (j0 < s1) ? expf(et0 - mt) : 0.f;
    float so = exo0, st = ext0;
    for (int j = j0 + 64; j < s1; j += 64) {
        float2 a2 = asv[csr_src[j]];
        float eo = a2.x + advv.x; eo = (eo > 0.f) ? eo : 0.2f * eo; so += expf(eo - mo);
        float et = a2.y + advv.y; et = (et > 0.f) ? et : 0.2f * et; st += expf(et - mt);
    }
#pragma unroll
    for (int o = 32; o; o >>= 1) { so += __shfl_xor(so, o); st += __shfl_xor(st, o); }
    float invo = 1.f / so, invt = 1.f / st;
    exo0 *= invo; ext0 *= invt;
    int sub = lane >> 4, c4 = lane & 15;
    float4 ao = make_float4(0.f, 0.f, 0.f, 0.f);
    float4 at4 = make_float4(0.f, 0.f, 0.f, 0.f);
    for (int cb = s0; cb < s1; cb += 64) {
        int sv; float wo, wt;
        if (cb == s0) { sv = sv0; wo = exo0; wt = ext0; }
        else {
            int jj = cb + lane; sv = 0; wo = 0.f; wt = 0.f;
            if (jj < s1) {
                sv = csr_src[jj];
                float2 a2 = asv[sv];
                float eo = a2.x + advv.x; eo = (eo > 0.f) ? eo : 0.2f * eo; wo = expf(eo - mo) * invo;
                float et = a2.y + advv.y; et = (et > 0.f) ? et : 0.2f * et; wt = expf(et - mt) * invt;
            }
        }
        int c = s1 - cb; if (c > 64) c = 64;
        int q = 0;
        for (; q + 8 <= c; q += 8) {
            int ilA = q + sub, ilB = q + 4 + sub;
            int sA = __shfl(sv, ilA), sB = __shfl(sv, ilB);
            float oA = __shfl(wo, ilA), oB = __shfl(wo, ilB);
            float tA = __shfl(wt, ilA), tB = __shfl(wt, ilB);
            const float* ha = h2 + (size_t)sA * 128 + (c4 << 2);
            const float* hb = h2 + (size_t)sB * 128 + (c4 << 2);
            float4 hoA = *(const float4*)ha;
            float4 htA = *(const float4*)(ha + 64);
            float4 hoB = *(const float4*)hb;
            float4 htB = *(const float4*)(hb + 64);
            ao.x += oA * hoA.x; ao.y += oA * hoA.y; ao.z += oA * hoA.z; ao.w += oA * hoA.w;
            at4.x += tA * htA.x; at4.y += tA * htA.y; at4.z += tA * htA.z; at4.w += tA * htA.w;
            ao.x += oB * hoB.x; ao.y += oB * hoB.y; ao.z += oB * hoB.z; ao.w += oB * hoB.w;
            at4.x += tB * htB.x; at4.y += tB * htB.y; at4.z += tB * htB.z; at4.w += tB * htB.w;
        }
        for (; q < c; q += 4) {
            int il = q + sub;
            int s = __shfl(sv, il);
            float o_ = __shfl(wo, il);
            float t_ = __shfl(wt, il);
            const float* hb = h2 + (size_t)s * 128 + (c4 << 2);
            float4 ho = *(const float4*)hb;
            float4 ht = *(const float4*)(hb + 64);
            ao.x += o_ * ho.x; ao.y += o_ * ho.y; ao.z += o_ * ho.z; ao.w += o_ * ho.w;
            at4.x += t_ * ht.x; at4.y += t_ * ht.y; at4.z += t_ * ht.z; at4.w += t_ * ht.w;
        }
    }
#pragma unroll
    for (int o = 16; o <= 32; o <<= 1) {
        ao.x += __shfl_xor(ao.x, o); ao.y += __shfl_xor(ao.y, o);
        ao.z += __shfl_xor(ao.z, o); ao.w += __shfl_xor(ao.w, o);
        at4.x += __shfl_xor(at4.x, o); at4.y += __shfl_xor(at4.y, o);
        at4.z += __shfl_xor(at4.z, o); at4.w += __shfl_xor(at4.w, o);
    }
    if (lane < 16) {
        float4 bo = ((const float4*)bias_o)[c4];
        ao.x += bo.x; ao.y += bo.y; ao.z += bo.z; ao.w += bo.w;
        ((float4*)po)[c4] = ao;
        float4 bt = ((const float4*)bias_t)[c4];
        at4.x += bt.x; at4.y += bt.y; at4.z += bt.z; at4.w += bt.w;
        ((float4*)pt)[c4] = at4;
    }
}

// merged predictor
__global__ __launch_bounds__(256) void k_pred2(const float* __restrict__ x, int nU, int nI,
                                               const float* __restrict__ W, const float* __restrict__ bvec,
                                               float* __restrict__ outU, float* __restrict__ outI) {
    __shared__ float sWt[64 * 65];
    int t = threadIdx.x;
#pragma unroll
    for (int u = 0; u < 16; u++) {
        int i = u * 256 + t;
        int c = i >> 6, k = i & 63;
        sWt[k * 65 + c] = W[i];
    }
    __syncthreads();
    int wid = t >> 6, lane = t & 63;
    int r = blockIdx.x * 4 + wid;
    if (r >= nU + nI) return;
    float xr = x[(size_t)r * 64 + lane];
    float acc = bvec[lane];
    for (int k = 0; k < 64; k++)
        acc += __shfl(xr, k) * sWt[k * 65 + lane];
    float* dst = (r < nU) ? (outU + (size_t)r * 64) : (outI + (size_t)(r - nU) * 64);
    dst[lane] = acc;
}

// ============ FALLBACK (sequential) kernels ============
__global__ void k_count(const int* __restrict__ dst_arr, int E, int N, int* __restrict__ cnt) {
    int e = blockIdx.x * blockDim.x + threadIdx.x;
    int ET = E + N;
    if (e < ET) {
        int d = (e < E) ? dst_arr[e] : (e - E);
        atomicAdd(&cnt[d], 1);
    }
}

__global__ void k_scatter(const int* __restrict__ src_arr, const int* __restrict__ dst_arr, int E, int N,
                          const int* __restrict__ row_ptr, int* __restrict__ cnt, int* __restrict__ csr_src) {
    int ET = E + N;
    int slice = blockIdx.x >> 3;
    int range = blockIdx.x & 7;
    int rsz = (N + 7) >> 3;
    int lo = range * rsz;
    int hi = lo + rsz; if (hi > N) hi = N;
    int base = slice * SLICE;
    int end = base + SLICE; if (end > ET) end = ET;
    for (int e = base + threadIdx.x; e < end; e += 256) {
        int s, d;
        if (e < E) { s = src_arr[e]; d = dst_arr[e]; }
        else { s = e - E; d = e - E; }
        if (d >= lo && d < hi) {
            int pos = atomicAdd(&cnt[d], 1);
            csr_src[row_ptr[d] + pos] = s;
        }
    }
}

__global__ __launch_bounds__(256) void k_gemm(const float* __restrict__ x,
                                              const float* __restrict__ ue, const float* __restrict__ ie, int NU,
                                              const float* __restrict__ W,
                                              const float* __restrict__ att_s, const float* __restrict__ att_d,
                                              float* __restrict__ h, float* __restrict__ as_, float* __restrict__ ad_,
                                              int N) {
    __shared__ float sW[64 * 64];
    __shared__ float sX[128 * 65];
    __shared__ float sAs[64], sAd[64];
    int t = threadIdx.x;
    int row0 = blockIdx.x * 128;
    {
        const float4* Wv = (const float4*)W;
        float4* sWv = (float4*)sW;
#pragma unroll
        for (int u = 0; u < 4; u++) sWv[t + 256 * u] = Wv[t + 256 * u];
    }
    if (t < 64) { sAs[t] = att_s[t]; sAd[t] = att_d[t]; }
    {
#pragma unroll
        for (int u = 0; u < 8; u++) {
            int idx = t + 256 * u;
            int r = idx >> 4, c4 = idx & 15;
            int grow = row0 + r;
            float4 v = make_float4(0.f, 0.f, 0.f, 0.f);
            if (grow < N) {
                const float* base = x ? (x + (size_t)grow * 64)
                                      : (grow < NU ? ue + (size_t)grow * 64 : ie + (size_t)(grow - NU) * 64);
                v = ((const float4*)base)[c4];
            }
            int cc = c4 * 4;
            sX[r * 65 + cc] = v.x; sX[r * 65 + cc + 1] = v.y; sX[r * 65 + cc + 2] = v.z; sX[r * 65 + cc + 3] = v.w;
        }
    }
    __syncthreads();
    int rl = t >> 2;
    int g = t & 3;
    int c0 = g * 16;
    int rA = rl * 2, rB = rA + 1;
    float accA[16], accB[16];
#pragma unroll
    for (int j = 0; j < 16; j++) { accA[j] = 0.f; accB[j] = 0.f; }
    for (int k = 0; k < 64; k++) {
        float xa = sX[rA * 65 + k];
        float xb = sX[rB * 65 + k];
        const float4* wr = (const float4*)&sW[k * 64 + c0];
        float4 w0 = wr[0], w1 = wr[1], w2 = wr[2], w3 = wr[3];
        accA[0] += xa * w0.x; accA[1] += xa * w0.y; accA[2] += xa * w0.z; accA[3] += xa * w0.w;
        accA[4] += xa * w1.x; accA[5] += xa * w1.y; accA[6] += xa * w1.z; accA[7] += xa * w1.w;
        accA[8] += xa * w2.x; accA[9] += xa * w2.y; accA[10] += xa * w2.z; accA[11] += xa * w2.w;
        accA[12] += xa * w3.x; accA[13] += xa * w3.y; accA[14] += xa * w3.z; accA[15] += xa * w3.w;
        accB[0] += xb * w0.x; accB[1] += xb * w0.y; accB[2] += xb * w0.z; accB[3] += xb * w0.w;
        accB[4] += xb * w1.x; accB[5] += xb * w1.y; accB[6] += xb * w1.z; accB[7] += xb * w1.w;
        accB[8] += xb * w2.x; accB[9] += xb * w2.y; accB[10] += xb * w2.z; accB[11] += xb * w2.w;
        accB[12] += xb * w3.x; accB[13] += xb * w3.y; accB[14] += xb * w3.z; accB[15] += xb * w3.w;
    }
    float sA = 0.f, dA = 0.f, sB = 0.f, dB = 0.f;
#pragma unroll
    for (int j = 0; j < 16; j++) {
        sA += accA[j] * sAs[c0 + j]; dA += accA[j] * sAd[c0 + j];
        sB += accB[j] * sAs[c0 + j]; dB += accB[j] * sAd[c0 + j];
    }
    sA += __shfl_xor(sA, 1); sA += __shfl_xor(sA, 2);
    dA += __shfl_xor(dA, 1); dA += __shfl_xor(dA, 2);
    sB += __shfl_xor(sB, 1); sB += __shfl_xor(sB, 2);
    dB += __shfl_xor(dB, 1); dB += __shfl_xor(dB, 2);
    int rowA = row0 + rA, rowB = row0 + rB;
    if (rowA < N) {
        if (g == 0) { as_[rowA] = sA; ad_[rowA] = dA; }
        float4* hv = (float4*)&h[(size_t)rowA * 64 + c0];
        hv[0] = make_float4(accA[0], accA[1], accA[2], accA[3]);
        hv[1] = make_float4(accA[4], accA[5], accA[6], accA[7]);
        hv[2] = make_float4(accA[8], accA[9], accA[10], accA[11]);
        hv[3] = make_float4(accA[12], accA[13], accA[14], accA[15]);
    }
    if (rowB < N) {
        if (g == 0) { as_[rowB] = sB; ad_[rowB] = dB; }
        float4* hv = (float4*)&h[(size_t)rowB * 64 + c0];
        hv[0] = make_float4(accB[0], accB[1], accB[2], accB[3]);
        hv[1] = make_float4(accB[4], accB[5], accB[6], accB[7]);
        hv[2] = make_float4(accB[8], accB[9], accB[10], accB[11]);
        hv[3] = make_float4(accB[12], accB[13], accB[14], accB[15]);
    }
}

__global__ __launch_bounds__(256) void k_agg(const float* __restrict__ h,
                                             const int* __restrict__ row_ptr, const int* __restrict__ csr_src,
                                             const float* __restrict__ as_, const float* __restrict__ ad_,
                                             const float* __restrict__ bias, float* __restrict__ xout, int N) {
    int wid = threadIdx.x >> 6, lane = threadIdx.x & 63;
    int d = blockIdx.x * 4 + wid;
    if (d >= N) return;
    int s0 = row_ptr[d], s1 = row_ptr[d + 1];
    float adv = ad_[d];
    int j0 = s0 + lane;
    int sv0 = 0; float ev0 = -1e30f;
    if (j0 < s1) {
        sv0 = csr_src[j0];
        float e = as_[sv0] + adv;
        ev0 = (e > 0.f) ? e : 0.2f * e;
    }
    float m = ev0;
    for (int j = j0 + 64; j < s1; j += 64) {
        float e = as_[csr_src[j]] + adv;
        e = (e > 0.f) ? e : 0.2f * e;
        m = fmaxf(m, e);
    }
#pragma unroll
    for (int o = 32; o; o >>= 1) m = fmaxf(m, __shfl_xor(m, o));
    float ex0 = (j0 < s1) ? expf(ev0 - m) : 0.f;
    float sum = ex0;
    for (int j = j0 + 64; j < s1; j += 64) {
        float e = as_[csr_src[j]] + adv;
        e = (e > 0.f) ? e : 0.2f * e;
        sum += expf(e - m);
    }
#pragma unroll
    for (int o = 32; o; o >>= 1) sum += __shfl_xor(sum, o);
    float inv = 1.f / sum;
    ex0 *= inv;
    int sub = lane >> 4;
    int c4 = lane & 15;
    float4 acc = make_float4(0.f, 0.f, 0.f, 0.f);
    for (int cbase = s0; cbase < s1; cbase += 64) {
        int sv; float ex;
        if (cbase == s0) { sv = sv0; ex = ex0; }
        else {
            int jj = cbase + lane;
            sv = 0; ex = 0.f;
            if (jj < s1) {
                sv = csr_src[jj];
                float e = as_[sv] + adv;
                e = (e > 0.f) ? e : 0.2f * e;
                ex = expf(e - m) * inv;
            }
        }
        int cnt2 = s1 - cbase; if (cnt2 > 64) cnt2 = 64;
        for (int q = 0; q < cnt2; q += 4) {
            int il = q + sub;
            float w = __shfl(ex, il);
            int s = __shfl(sv, il);
            const float4 hv = *(const float4*)&h[(size_t)s * 64 + (c4 << 2)];
            acc.x += w * hv.x; acc.y += w * hv.y; acc.z += w * hv.z; acc.w += w * hv.w;
        }
    }
#pragma unroll
    for (int o = 16; o <= 32; o <<= 1) {
        acc.x += __shfl_xor(acc.x, o);
        acc.y += __shfl_xor(acc.y, o);
        acc.z += __shfl_xor(acc.z, o);
        acc.w += __shfl_xor(acc.w, o);
    }
    if (lane < 16) {
        float4 bv = ((const float4*)bias)[c4];
        acc.x += bv.x; acc.y += bv.y; acc.z += bv.z; acc.w += bv.w;
        ((float4*)&xout[(size_t)d * 64])[c4] = acc;
    }
}

__global__ __launch_bounds__(256) void k_pred(const float* __restrict__ x, const int* __restrict__ idx,
                                              int nIdx, int rowOff, const float* __restrict__ W,
                                              const float* __restrict__ bvec, float* __restrict__ out) {
    __shared__ float sWt[64 * 65];
    int t = threadIdx.x;
#pragma unroll
    for (int u = 0; u < 16; u++) {
        int i = u * 256 + t;
        int c = i >> 6, k = i & 63;
        sWt[k * 65 + c] = W[i];
    }
    __syncthreads();
    int wid = t >> 6, lane = t & 63;
    int r = blockIdx.x * 4 + wid;
    if (r >= nIdx) return;
    int node = idx ? (idx[r] + rowOff) : (r + rowOff);
    float xr = x[(size_t)node * 64 + lane];
    float acc = bvec[lane];
    for (int k = 0; k < 64; k++)
        acc += __shfl(xr, k) * sWt[k * 65 + lane];
    out[(size_t)r * 64 + lane] = acc;
}

__global__ void k_gather(const float* __restrict__ x, const int* __restrict__ idx, int nIdx, int rowOff,
                         float* __restrict__ out) {
    int t = blockIdx.x * blockDim.x + threadIdx.x;
    if (t < nIdx * 64) {
        int r = t >> 6, c = t & 63;
        int node = idx[r] + rowOff;
        out[t] = x[(size_t)node * 64 + c];
    }
}

extern "C" void kernel_launch(void* const* d_in, const int* in_sizes, int n_in,
                              void* d_out, int out_size, void* d_ws, size_t ws_size,
                              hipStream_t stream) {
    const int* user = (const int*)d_in[0];
    const int* item = (const int*)d_in[1];
    const int* edge = (const int*)d_in[2];
    const float* user_emb_o = (const float*)d_in[3];
    const float* item_emb_o = (const float*)d_in[4];
    const float* W_o = (const float*)d_in[5];
    const float* att_src_o = (const float*)d_in[6];
    const float* att_dst_o = (const float*)d_in[7];
    const float* bias_o = (const float*)d_in[8];
    const float* user_emb_t = (const float*)d_in[9];
    const float* item_emb_t = (const float*)d_in[10];
    const float* W_t = (const float*)d_in[11];
    const float* att_src_t = (const float*)d_in[12];
    const float* att_dst_t = (const float*)d_in[13];
    const float* bias_t = (const float*)d_in[14];
    const float* pred_W = (const float*)d_in[15];
    const float* pred_b = (const float*)d_in[16];
    float* out = (float*)d_out;

    int E = in_sizes[2] / 2;
    int NU = in_sizes[3] / LAT;
    int NI = in_sizes[4] / LAT;
    int N = NU + NI;
    int ET = E + N;
    int nU = in_sizes[0];
    int nI = in_sizes[1];
    int nSel = nU + nI;
    int rsz = (N + 7) >> 3;

    const int* src_arr = edge;
    const int* dst_arr = edge + E;

    auto al = [](size_t v) { return (v + 255) & ~(size_t)255; };

    // ---- primary layout (h2 ping-pong; x never materialized) ----
    char* p = (char*)d_ws;
    float* h2a   = (float*)p;  p += al((size_t)N * 2 * LAT * 4);
    float* h2b   = (float*)p;  p += al((size_t)N * 2 * LAT * 4);
    float* asa   = (float*)p;  p += al((size_t)N * 8);
    float* ada   = (float*)p;  p += al((size_t)N * 8);
    float* asb   = (float*)p;  p += al((size_t)N * 8);
    float* adb   = (float*)p;  p += al((size_t)N * 8);
    int* row_ptr = (int*)p;    p += al((size_t)(N + 1) * 4);
    int* cnt     = (int*)p;    size_t cntsz = al((size_t)N * 4); p += cntsz;
    int* gcur    = (int*)p;    p += al(64);
    int* csr_src = (int*)p;    p += al((size_t)ET * 4);
    int* blk     = (int*)p;    p += al(4096);
    float* xsel  = (float*)p;  p += al((size_t)nSel * LAT * 4);
    size_t need_primary = (size_t)(p - (char*)d_ws);

    // buckets alias h2b (binB completes before fagg0 writes h2b)
    int bcap = ET / 8 + 16384;
    int2* buckets = (int2*)h2b;

    bool primary = ws_size >= need_primary;

    if (primary) {
        int gemmGrid = cdiv(N, 128) * 2;
        int binGrid = 1024;
        hipMemsetAsync(cnt, 0, cntsz + 64, stream);   // cnt + gcur (contiguous)
        // fused: layer-0 gemm (both encoders) -> h2a + edge binning w/ degree count
        k_l0<<<gemmGrid + binGrid, 256, 0, stream>>>(
                user_emb_o, item_emb_o, user_emb_t, item_emb_t, NU,
                W_o, W_t, att_src_o, att_dst_o, att_src_t, att_dst_t,
                h2a, asa, ada, N,
                gemmGrid, binGrid,
                src_arr, dst_arr, E, ET, rsz, bcap,
                buckets, gcur, cnt);
        int NB = cdiv(N, 1024);
        k_scan1<<<NB, 256, 0, stream>>>(cnt, N, row_ptr, blk);
        k_scan2<<<1, 256, 0, stream>>>(blk, NB);
        k_scan3<<<NB, 256, 0, stream>>>(row_ptr, blk, N, ET);
        hipMemsetAsync(cnt, 0, (size_t)N * 4, stream);
        k_binB<<<1024, 256, 0, stream>>>(buckets, bcap, gcur, row_ptr, cnt, csr_src);

        // fused agg(l0)+transform(W1): h2a -> h2b, scores a -> b
        k_fagg<<<cdiv(N, 4) * 2, 256, 0, stream>>>(h2a, row_ptr, csr_src, asa, ada,
                bias_o, bias_t,
                W_o + 4096, W_t + 4096,
                att_src_o + 64, att_dst_o + 64, att_src_t + 64, att_dst_t + 64,
                h2b, asb, adb, N);
        // fused agg(l1)+transform(W2): h2b -> h2a, scores b -> a
        k_fagg<<<cdiv(N, 4) * 2, 256, 0, stream>>>(h2b, row_ptr, csr_src, asb, adb,
                bias_o + 64, bias_t + 64,
                W_o + 2 * 4096, W_t + 2 * 4096,
                att_src_o + 128, att_dst_o + 128, att_src_t + 128, att_dst_t + 128,
                h2a, asa, ada, N);
        // final selective agg (layer 2): target -> d_out, online -> xsel
        k_agg2<<<cdiv(nSel, 4), 256, 0, stream>>>(h2a, row_ptr, csr_src,
                (const float2*)asa, (const float2*)ada,
                bias_o + 128, bias_t + 128,
                nullptr, nullptr, N,
                user, item, nSel, nU, NU,
                xsel, out + (size_t)nU * LAT, out + (size_t)3 * nU * LAT);
        k_pred2<<<cdiv(nSel, 4), 256, 0, stream>>>(xsel, nU, nI, pred_W, pred_b,
                                                   out, out + (size_t)2 * nU * LAT);
        return;
    }

    // ---- fallback: sequential encoders ----
    p = (char*)d_ws;
    float* x_cur = (float*)p;  p += al((size_t)N * LAT * 4);
    float* h     = (float*)p;  p += al((size_t)N * LAT * 4);
    float* as_   = (float*)p;  p += al((size_t)N * 4);
    float* ad_   = (float*)p;  p += al((size_t)N * 4);
    row_ptr = (int*)p;         p += al((size_t)(N + 1) * 4);
    cnt     = (int*)p;         p += al((size_t)N * 4);
    csr_src = (int*)p;         p += al((size_t)ET * 4);
    blk     = (int*)p;         p += al(4096);

    hipMemsetAsync(cnt, 0, (size_t)N * 4, stream);
    k_count<<<cdiv(ET, 256), 256, 0, stream>>>(dst_arr, E, N, cnt);
    int NB = cdiv(N, 1024);
    k_scan1<<<NB, 256, 0, stream>>>(cnt, N, row_ptr, blk);
    k_scan2<<<1, 256, 0, stream>>>(blk, NB);
    k_scan3<<<NB, 256, 0, stream>>>(row_ptr, blk, N, ET);
    hipMemsetAsync(cnt, 0, (size_t)N * 4, stream);
    k_scatter<<<cdiv(ET, SLICE) * 8, 256, 0, stream>>>(src_arr, dst_arr, E, N, row_ptr, cnt, csr_src);

    auto run_encoder = [&](const float* ue, const float* ie, const float* Wl,
                           const float* asl, const float* adl, const float* bl) {
        for (int l = 0; l < 3; l++) {
            const float* xin = (l == 0) ? nullptr : x_cur;
            k_gemm<<<cdiv(N, 128), 256, 0, stream>>>(xin, ue, ie, NU, Wl + l * 64 * 64, asl + l * 64,
                                                     adl + l * 64, h, as_, ad_, N);
            k_agg<<<cdiv(N, 4), 256, 0, stream>>>(h, row_ptr, csr_src, as_, ad_, bl + l * 64, x_cur, N);
        }
    };

    run_encoder(user_emb_o, item_emb_o, W_o, att_src_o, att_dst_o, bias_o);
    k_pred<<<cdiv(nU, 4), 256, 0, stream>>>(x_cur, user, nU, 0, pred_W, pred_b, out);
    k_pred<<<cdiv(nI, 4), 256, 0, stream>>>(x_cur, item, nI, NU, pred_W, pred_b, out + (size_t)2 * nU * LAT);

    run_encoder(user_emb_t, item_emb_t, W_t, att_src_t, att_dst_t, bias_t);
    k_gather<<<cdiv(nU * LAT, 256), 256, 0, stream>>>(x_cur, user, nU, 0, out + (size_t)nU * LAT);
    k_gather<<<cdiv(nI * LAT, 256), 256, 0, stream>>>(x_cur, item, nI, NU, out + (size_t)3 * nU * LAT);
}

// Round 10
// 835.926 us; speedup vs baseline: 1.3785x; 1.3785x over previous
//
#include <hip/hip_runtime.h>
#include <math.h>
#include <stdint.h>

#define LAT 64
#define SLICE 16384
#define BIN_CHUNK 1024

static inline int cdiv(int a, int b) { return (a + b - 1) / b; }

// ---------------- scans ----------------
__global__ void k_scan1(const int* __restrict__ cnt, int N, int* __restrict__ out, int* __restrict__ blk_sums) {
    __shared__ int sdata[256];
    int t = threadIdx.x, b = blockIdx.x;
    int base = b * 1024 + t * 4;
    int v[4];
    int s = 0;
#pragma unroll
    for (int u = 0; u < 4; u++) { int i = base + u; v[u] = (i < N) ? cnt[i] : 0; s += v[u]; }
    sdata[t] = s; __syncthreads();
    for (int off = 1; off < 256; off <<= 1) {
        int x = (t >= off) ? sdata[t - off] : 0;
        __syncthreads();
        sdata[t] += x;
        __syncthreads();
    }
    int run = sdata[t] - s;
#pragma unroll
    for (int u = 0; u < 4; u++) { int i = base + u; if (i < N) out[i] = run; run += v[u]; }
    if (t == 255) blk_sums[b] = sdata[255];
}

__global__ void k_scan2(int* __restrict__ blk_sums, int NB) {
    __shared__ int sdata[256];
    int t = threadIdx.x;
    int v = (t < NB) ? blk_sums[t] : 0;
    sdata[t] = v; __syncthreads();
    for (int off = 1; off < 256; off <<= 1) {
        int x = (t >= off) ? sdata[t - off] : 0;
        __syncthreads();
        sdata[t] += x;
        __syncthreads();
    }
    if (t < NB) blk_sums[t] = sdata[t] - v;  // exclusive
}

__global__ void k_scan3(int* __restrict__ row_ptr, const int* __restrict__ blk_offs, int N, int ET) {
    int t = threadIdx.x, b = blockIdx.x;
    int base = b * 1024 + t * 4;
    int off = blk_offs[b];
#pragma unroll
    for (int u = 0; u < 4; u++) { int i = base + u; if (i < N) row_ptr[i] += off; }
    if (b == 0 && t == 0) row_ptr[N] = ET;
}

// ---------------- fused layer-0 transform + binA ----------------
// Blocks [0, gemmGrid): layer-0 GEMM for both encoders (enc = blockIdx&1).
// Blocks [gemmGrid, gemmGrid+binGrid): edge binning (8 dst-range buckets,
// coalesced 1KB runs, degree count fused). Independent work co-scheduled to
// overlap VALU-heavy gemm with memory-heavy binning.
__global__ __launch_bounds__(256) void k_l0(
        const float* __restrict__ ueo, const float* __restrict__ ieo,
        const float* __restrict__ uet, const float* __restrict__ iet, int NU,
        const float* __restrict__ Wo, const float* __restrict__ Wt,
        const float* __restrict__ atso, const float* __restrict__ atdo,
        const float* __restrict__ atst, const float* __restrict__ atdt,
        float* __restrict__ h2, float* __restrict__ asp, float* __restrict__ adp, int N,
        int gemmGrid, int binGrid,
        const int* __restrict__ src_arr, const int* __restrict__ dst_arr,
        int E, int ET, int rsz, int bcap,
        int2* __restrict__ buckets, int* __restrict__ gcur, int* __restrict__ cnt) {
    __shared__ float sW[64 * 64];
    __shared__ float sX[128 * 65];
    __shared__ float sAs[64], sAd[64];
    int t = threadIdx.x;

    if ((int)blockIdx.x >= gemmGrid) {
        // ---- binA body ----
        int* lcnt = (int*)sW;
        int* lbase = (int*)sW + 8;
        int bb = blockIdx.x - gemmGrid;
        for (int base = bb * BIN_CHUNK; base < ET; base += binGrid * BIN_CHUNK) {
            if (t < 8) lcnt[t] = 0;
            __syncthreads();
            int s[4], d[4], r[4], lofs[4];
            int nval = 0;
            if (base + BIN_CHUNK <= E) {
                int4 s4 = ((const int4*)(src_arr + base))[t];
                int4 d4 = ((const int4*)(dst_arr + base))[t];
                s[0] = s4.x; s[1] = s4.y; s[2] = s4.z; s[3] = s4.w;
                d[0] = d4.x; d[1] = d4.y; d[2] = d4.z; d[3] = d4.w;
                nval = 4;
            } else {
                for (int k = 0; k < 4; k++) {
                    int e = base + t * 4 + k;
                    if (e < ET) {
                        if (e < E) { s[nval] = src_arr[e]; d[nval] = dst_arr[e]; }
                        else { s[nval] = e - E; d[nval] = e - E; }
                        nval++;
                    }
                }
            }
            for (int k = 0; k < nval; k++) {
                r[k] = d[k] / rsz;
                lofs[k] = atomicAdd(&lcnt[r[k]], 1);
                atomicAdd(&cnt[d[k]], 1);
            }
            __syncthreads();
            if (t < 8) lbase[t] = atomicAdd(&gcur[t], lcnt[t]);
            __syncthreads();
            for (int k = 0; k < nval; k++) {
                buckets[(size_t)r[k] * bcap + lbase[r[k]] + lofs[k]] = make_int2(s[k], d[k]);
            }
            __syncthreads();
        }
        return;
    }

    // ---- layer-0 gemm body ----
    int enc = blockIdx.x & 1;
    int bb = blockIdx.x >> 1;
    const float* ue = enc ? uet : ueo;
    const float* ie = enc ? iet : ieo;
    const float* W = enc ? Wt : Wo;
    const float* att_s = enc ? atst : atso;
    const float* att_d = enc ? atdt : atdo;
    float* h2e = h2 + enc * 64;
    int row0 = bb * 128;
    {
        const float4* Wv = (const float4*)W;
        float4* sWv = (float4*)sW;
#pragma unroll
        for (int u = 0; u < 4; u++) sWv[t + 256 * u] = Wv[t + 256 * u];
    }
    if (t < 64) { sAs[t] = att_s[t]; sAd[t] = att_d[t]; }
    {
#pragma unroll
        for (int u = 0; u < 8; u++) {
            int idx = t + 256 * u;
            int r = idx >> 4, c4 = idx & 15;
            int grow = row0 + r;
            float4 v = make_float4(0.f, 0.f, 0.f, 0.f);
            if (grow < N) {
                const float* base = (grow < NU) ? ue + (size_t)grow * 64 : ie + (size_t)(grow - NU) * 64;
                v = ((const float4*)base)[c4];
            }
            int cc = c4 * 4;
            sX[r * 65 + cc] = v.x; sX[r * 65 + cc + 1] = v.y; sX[r * 65 + cc + 2] = v.z; sX[r * 65 + cc + 3] = v.w;
        }
    }
    __syncthreads();
    int rl = t >> 2;
    int g = t & 3;
    int c0 = g * 16;
    int rA = rl * 2, rB = rA + 1;
    float accA[16], accB[16];
#pragma unroll
    for (int j = 0; j < 16; j++) { accA[j] = 0.f; accB[j] = 0.f; }
    for (int k = 0; k < 64; k++) {
        float xa = sX[rA * 65 + k];
        float xb = sX[rB * 65 + k];
        const float4* wr = (const float4*)&sW[k * 64 + c0];
        float4 w0 = wr[0], w1 = wr[1], w2 = wr[2], w3 = wr[3];
        accA[0] += xa * w0.x; accA[1] += xa * w0.y; accA[2] += xa * w0.z; accA[3] += xa * w0.w;
        accA[4] += xa * w1.x; accA[5] += xa * w1.y; accA[6] += xa * w1.z; accA[7] += xa * w1.w;
        accA[8] += xa * w2.x; accA[9] += xa * w2.y; accA[10] += xa * w2.z; accA[11] += xa * w2.w;
        accA[12] += xa * w3.x; accA[13] += xa * w3.y; accA[14] += xa * w3.z; accA[15] += xa * w3.w;
        accB[0] += xb * w0.x; accB[1] += xb * w0.y; accB[2] += xb * w0.z; accB[3] += xb * w0.w;
        accB[4] += xb * w1.x; accB[5] += xb * w1.y; accB[6] += xb * w1.z; accB[7] += xb * w1.w;
        accB[8] += xb * w2.x; accB[9] += xb * w2.y; accB[10] += xb * w2.z; accB[11] += xb * w2.w;
        accB[12] += xb * w3.x; accB[13] += xb * w3.y; accB[14] += xb * w3.z; accB[15] += xb * w3.w;
    }
    float sA = 0.f, dA = 0.f, sB = 0.f, dB = 0.f;
#pragma unroll
    for (int j = 0; j < 16; j++) {
        sA += accA[j] * sAs[c0 + j]; dA += accA[j] * sAd[c0 + j];
        sB += accB[j] * sAs[c0 + j]; dB += accB[j] * sAd[c0 + j];
    }
    sA += __shfl_xor(sA, 1); sA += __shfl_xor(sA, 2);
    dA += __shfl_xor(dA, 1); dA += __shfl_xor(dA, 2);
    sB += __shfl_xor(sB, 1); sB += __shfl_xor(sB, 2);
    dB += __shfl_xor(dB, 1); dB += __shfl_xor(dB, 2);
    int rowA = row0 + rA, rowB = row0 + rB;
    if (rowA < N) {
        if (g == 0) { asp[(size_t)rowA * 2 + enc] = sA; adp[(size_t)rowA * 2 + enc] = dA; }
        float4* hv = (float4*)&h2e[(size_t)rowA * 128 + c0];
        hv[0] = make_float4(accA[0], accA[1], accA[2], accA[3]);
        hv[1] = make_float4(accA[4], accA[5], accA[6], accA[7]);
        hv[2] = make_float4(accA[8], accA[9], accA[10], accA[11]);
        hv[3] = make_float4(accA[12], accA[13], accA[14], accA[15]);
    }
    if (rowB < N) {
        if (g == 0) { asp[(size_t)rowB * 2 + enc] = sB; adp[(size_t)rowB * 2 + enc] = dB; }
        float4* hv = (float4*)&h2e[(size_t)rowB * 128 + c0];
        hv[0] = make_float4(accB[0], accB[1], accB[2], accB[3]);
        hv[1] = make_float4(accB[4], accB[5], accB[6], accB[7]);
        hv[2] = make_float4(accB[8], accB[9], accB[10], accB[11]);
        hv[3] = make_float4(accB[12], accB[13], accB[14], accB[15]);
    }
}

// Phase B: XCD-affine scatter from buckets.
__global__ __launch_bounds__(256) void k_binB(const int2* __restrict__ buckets, int bcap,
                                              const int* __restrict__ gcur,
                                              const int* __restrict__ row_ptr, int* __restrict__ cnt,
                                              int* __restrict__ csr_src) {
    int r = blockIdx.x & 7;
    int nb = blockIdx.x >> 3;
    int stride = (gridDim.x >> 3) * 256;
    int total = gcur[r];
    const int* bp = (const int*)(buckets + (size_t)r * bcap);
    for (int i = nb * 256 + threadIdx.x; i < total; i += stride) {
        int s = __builtin_nontemporal_load(bp + 2 * i);
        int d = __builtin_nontemporal_load(bp + 2 * i + 1);
        int pos = atomicAdd(&cnt[d], 1);
        csr_src[row_ptr[d] + pos] = s;
    }
}

// ---------------- merged-encoder transform (layers 1,2) ----------------
__global__ __launch_bounds__(256) void k_gemm2m(const float* __restrict__ xo, const float* __restrict__ xt,
        int NU,
        const float* __restrict__ Wo, const float* __restrict__ Wt,
        const float* __restrict__ atso, const float* __restrict__ atdo,
        const float* __restrict__ atst, const float* __restrict__ atdt,
        float* __restrict__ h2, float* __restrict__ asp, float* __restrict__ adp, int N) {
    __shared__ float sW[64 * 64];
    __shared__ float sX[128 * 65];
    __shared__ float sAs[64], sAd[64];
    int enc = blockIdx.x & 1;
    int bb = blockIdx.x >> 1;
    const float* x = enc ? xt : xo;
    const float* W = enc ? Wt : Wo;
    const float* att_s = enc ? atst : atso;
    const float* att_d = enc ? atdt : atdo;
    float* h2e = h2 + enc * 64;
    int t = threadIdx.x;
    int row0 = bb * 128;
    {
        const float4* Wv = (const float4*)W;
        float4* sWv = (float4*)sW;
#pragma unroll
        for (int u = 0; u < 4; u++) sWv[t + 256 * u] = Wv[t + 256 * u];
    }
    if (t < 64) { sAs[t] = att_s[t]; sAd[t] = att_d[t]; }
    {
#pragma unroll
        for (int u = 0; u < 8; u++) {
            int idx = t + 256 * u;
            int r = idx >> 4, c4 = idx & 15;
            int grow = row0 + r;
            float4 v = make_float4(0.f, 0.f, 0.f, 0.f);
            if (grow < N) v = ((const float4*)(x + (size_t)grow * 64))[c4];
            int cc = c4 * 4;
            sX[r * 65 + cc] = v.x; sX[r * 65 + cc + 1] = v.y; sX[r * 65 + cc + 2] = v.z; sX[r * 65 + cc + 3] = v.w;
        }
    }
    __syncthreads();
    int rl = t >> 2;
    int g = t & 3;
    int c0 = g * 16;
    int rA = rl * 2, rB = rA + 1;
    float accA[16], accB[16];
#pragma unroll
    for (int j = 0; j < 16; j++) { accA[j] = 0.f; accB[j] = 0.f; }
    for (int k = 0; k < 64; k++) {
        float xa = sX[rA * 65 + k];
        float xb = sX[rB * 65 + k];
        const float4* wr = (const float4*)&sW[k * 64 + c0];
        float4 w0 = wr[0], w1 = wr[1], w2 = wr[2], w3 = wr[3];
        accA[0] += xa * w0.x; accA[1] += xa * w0.y; accA[2] += xa * w0.z; accA[3] += xa * w0.w;
        accA[4] += xa * w1.x; accA[5] += xa * w1.y; accA[6] += xa * w1.z; accA[7] += xa * w1.w;
        accA[8] += xa * w2.x; accA[9] += xa * w2.y; accA[10] += xa * w2.z; accA[11] += xa * w2.w;
        accA[12] += xa * w3.x; accA[13] += xa * w3.y; accA[14] += xa * w3.z; accA[15] += xa * w3.w;
        accB[0] += xb * w0.x; accB[1] += xb * w0.y; accB[2] += xb * w0.z; accB[3] += xb * w0.w;
        accB[4] += xb * w1.x; accB[5] += xb * w1.y; accB[6] += xb * w1.z; accB[7] += xb * w1.w;
        accB[8] += xb * w2.x; accB[9] += xb * w2.y; accB[10] += xb * w2.z; accB[11] += xb * w2.w;
        accB[12] += xb * w3.x; accB[13] += xb * w3.y; accB[14] += xb * w3.z; accB[15] += xb * w3.w;
    }
    float sA = 0.f, dA = 0.f, sB = 0.f, dB = 0.f;
#pragma unroll
    for (int j = 0; j < 16; j++) {
        sA += accA[j] * sAs[c0 + j]; dA += accA[j] * sAd[c0 + j];
        sB += accB[j] * sAs[c0 + j]; dB += accB[j] * sAd[c0 + j];
    }
    sA += __shfl_xor(sA, 1); sA += __shfl_xor(sA, 2);
    dA += __shfl_xor(dA, 1); dA += __shfl_xor(dA, 2);
    sB += __shfl_xor(sB, 1); sB += __shfl_xor(sB, 2);
    dB += __shfl_xor(dB, 1); dB += __shfl_xor(dB, 2);
    int rowA = row0 + rA, rowB = row0 + rB;
    if (rowA < N) {
        if (g == 0) { asp[(size_t)rowA * 2 + enc] = sA; adp[(size_t)rowA * 2 + enc] = dA; }
        float4* hv = (float4*)&h2e[(size_t)rowA * 128 + c0];
        hv[0] = make_float4(accA[0], accA[1], accA[2], accA[3]);
        hv[1] = make_float4(accA[4], accA[5], accA[6], accA[7]);
        hv[2] = make_float4(accA[8], accA[9], accA[10], accA[11]);
        hv[3] = make_float4(accA[12], accA[13], accA[14], accA[15]);
    }
    if (rowB < N) {
        if (g == 0) { asp[(size_t)rowB * 2 + enc] = sB; adp[(size_t)rowB * 2 + enc] = dB; }
        float4* hv = (float4*)&h2e[(size_t)rowB * 128 + c0];
        hv[0] = make_float4(accB[0], accB[1], accB[2], accB[3]);
        hv[1] = make_float4(accB[4], accB[5], accB[6], accB[7]);
        hv[2] = make_float4(accB[8], accB[9], accB[10], accB[11]);
        hv[3] = make_float4(accB[12], accB[13], accB[14], accB[15]);
    }
}

// ---------------- combined-encoder softmax-aggregate ----------------
__global__ __launch_bounds__(256) void k_agg2(const float* __restrict__ h2,
                                              const int* __restrict__ row_ptr, const int* __restrict__ csr_src,
                                              const float2* __restrict__ asv, const float2* __restrict__ adv,
                                              const float* __restrict__ bias_o, const float* __restrict__ bias_t,
                                              float* __restrict__ xo, float* __restrict__ xt, int N,
                                              const int* __restrict__ selu, const int* __restrict__ seli,
                                              int nSel, int nSelU, int NU,
                                              float* __restrict__ selxo, float* __restrict__ outT_u,
                                              float* __restrict__ outT_i) {
    int wid = threadIdx.x >> 6, lane = threadIdx.x & 63;
    int r = blockIdx.x * 4 + wid;
    int d;
    float *po, *pt;
    if (selu) {
        if (r >= nSel) return;
        if (r < nSelU) { d = selu[r]; pt = outT_u + (size_t)r * 64; }
        else { int rr = r - nSelU; d = seli[rr] + NU; pt = outT_i + (size_t)rr * 64; }
        po = selxo + (size_t)r * 64;
    } else {
        if (r >= N) return;
        d = r;
        po = xo + (size_t)d * 64;
        pt = xt + (size_t)d * 64;
    }
    int s0 = row_ptr[d], s1 = row_ptr[d + 1];
    float2 advv = adv[d];
    int j0 = s0 + lane;
    int sv0 = 0; float eo0 = -1e30f, et0 = -1e30f;
    if (j0 < s1) {
        sv0 = csr_src[j0];
        float2 a2 = asv[sv0];
        float eo = a2.x + advv.x; eo0 = (eo > 0.f) ? eo : 0.2f * eo;
        float et = a2.y + advv.y; et0 = (et > 0.f) ? et : 0.2f * et;
    }
    float mo = eo0, mt = et0;
    for (int j = j0 + 64; j < s1; j += 64) {   // rare: deg > 64
        float2 a2 = asv[csr_src[j]];
        float eo = a2.x + advv.x; eo = (eo > 0.f) ? eo : 0.2f * eo; mo = fmaxf(mo, eo);
        float et = a2.y + advv.y; et = (et > 0.f) ? et : 0.2f * et; mt = fmaxf(mt, et);
    }
#pragma unroll
    for (int o = 32; o; o >>= 1) { mo = fmaxf(mo, __shfl_xor(mo, o)); mt = fmaxf(mt, __shfl_xor(mt, o)); }
    float exo0 = (j0 < s1) ? expf(eo0 - mo) : 0.f;
    float ext0 = (j0 < s1) ? expf(et0 - mt) : 0.f;
    float so = exo0, st = ext0;
    for (int j = j0 + 64; j < s1; j += 64) {   // rare
        float2 a2 = asv[csr_src[j]];
        float eo = a2.x + advv.x; eo = (eo > 0.f) ? eo : 0.2f * eo; so += expf(eo - mo);
        float et = a2.y + advv.y; et = (et > 0.f) ? et : 0.2f * et; st += expf(et - mt);
    }
#pragma unroll
    for (int o = 32; o; o >>= 1) { so += __shfl_xor(so, o); st += __shfl_xor(st, o); }
    float invo = 1.f / so, invt = 1.f / st;
    exo0 *= invo; ext0 *= invt;
    int sub = lane >> 4, c4 = lane & 15;
    float4 ao = make_float4(0.f, 0.f, 0.f, 0.f);
    float4 at4 = make_float4(0.f, 0.f, 0.f, 0.f);
    for (int cb = s0; cb < s1; cb += 64) {
        int sv; float wo, wt;
        if (cb == s0) { sv = sv0; wo = exo0; wt = ext0; }
        else {                                    // rare: deg > 64
            int jj = cb + lane; sv = 0; wo = 0.f; wt = 0.f;
            if (jj < s1) {
                sv = csr_src[jj];
                float2 a2 = asv[sv];
                float eo = a2.x + advv.x; eo = (eo > 0.f) ? eo : 0.2f * eo; wo = expf(eo - mo) * invo;
                float et = a2.y + advv.y; et = (et > 0.f) ? et : 0.2f * et; wt = expf(et - mt) * invt;
            }
        }
        int c = s1 - cb; if (c > 64) c = 64;
        int q = 0;
        for (; q + 8 <= c; q += 8) {
            int ilA = q + sub, ilB = q + 4 + sub;
            int sA = __shfl(sv, ilA), sB = __shfl(sv, ilB);
            float oA = __shfl(wo, ilA), oB = __shfl(wo, ilB);
            float tA = __shfl(wt, ilA), tB = __shfl(wt, ilB);
            const float* ha = h2 + (size_t)sA * 128 + (c4 << 2);
            const float* hb = h2 + (size_t)sB * 128 + (c4 << 2);
            float4 hoA = *(const float4*)ha;
            float4 htA = *(const float4*)(ha + 64);
            float4 hoB = *(const float4*)hb;
            float4 htB = *(const float4*)(hb + 64);
            ao.x += oA * hoA.x; ao.y += oA * hoA.y; ao.z += oA * hoA.z; ao.w += oA * hoA.w;
            at4.x += tA * htA.x; at4.y += tA * htA.y; at4.z += tA * htA.z; at4.w += tA * htA.w;
            ao.x += oB * hoB.x; ao.y += oB * hoB.y; ao.z += oB * hoB.z; ao.w += oB * hoB.w;
            at4.x += tB * htB.x; at4.y += tB * htB.y; at4.z += tB * htB.z; at4.w += tB * htB.w;
        }
        for (; q < c; q += 4) {
            int il = q + sub;
            int s = __shfl(sv, il);
            float o_ = __shfl(wo, il);
            float t_ = __shfl(wt, il);
            const float* hb = h2 + (size_t)s * 128 + (c4 << 2);
            float4 ho = *(const float4*)hb;
            float4 ht = *(const float4*)(hb + 64);
            ao.x += o_ * ho.x; ao.y += o_ * ho.y; ao.z += o_ * ho.z; ao.w += o_ * ho.w;
            at4.x += t_ * ht.x; at4.y += t_ * ht.y; at4.z += t_ * ht.z; at4.w += t_ * ht.w;
        }
    }
#pragma unroll
    for (int o = 16; o <= 32; o <<= 1) {
        ao.x += __shfl_xor(ao.x, o); ao.y += __shfl_xor(ao.y, o);
        ao.z += __shfl_xor(ao.z, o); ao.w += __shfl_xor(ao.w, o);
        at4.x += __shfl_xor(at4.x, o); at4.y += __shfl_xor(at4.y, o);
        at4.z += __shfl_xor(at4.z, o); at4.w += __shfl_xor(at4.w, o);
    }
    if (lane < 16) {
        float4 bo = ((const float4*)bias_o)[c4];
        ao.x += bo.x; ao.y += bo.y; ao.z += bo.z; ao.w += bo.w;
        ((float4*)po)[c4] = ao;
        float4 bt = ((const float4*)bias_t)[c4];
        at4.x += bt.x; at4.y += bt.y; at4.z += bt.z; at4.w += bt.w;
        ((float4*)pt)[c4] = at4;
    }
}

// merged predictor: rows [0,nU) = users -> outU, [nU,nU+nI) = items -> outI
__global__ __launch_bounds__(256) void k_pred2(const float* __restrict__ x, int nU, int nI,
                                               const float* __restrict__ W, const float* __restrict__ bvec,
                                               float* __restrict__ outU, float* __restrict__ outI) {
    __shared__ float sWt[64 * 65];
    int t = threadIdx.x;
#pragma unroll
    for (int u = 0; u < 16; u++) {
        int i = u * 256 + t;
        int c = i >> 6, k = i & 63;
        sWt[k * 65 + c] = W[i];
    }
    __syncthreads();
    int wid = t >> 6, lane = t & 63;
    int r = blockIdx.x * 4 + wid;
    if (r >= nU + nI) return;
    float xr = x[(size_t)r * 64 + lane];
    float acc = bvec[lane];
    for (int k = 0; k < 64; k++)
        acc += __shfl(xr, k) * sWt[k * 65 + lane];
    float* dst = (r < nU) ? (outU + (size_t)r * 64) : (outI + (size_t)(r - nU) * 64);
    dst[lane] = acc;
}

// ============ FALLBACK (sequential) kernels ============
__global__ void k_count(const int* __restrict__ dst_arr, int E, int N, int* __restrict__ cnt) {
    int e = blockIdx.x * blockDim.x + threadIdx.x;
    int ET = E + N;
    if (e < ET) {
        int d = (e < E) ? dst_arr[e] : (e - E);
        atomicAdd(&cnt[d], 1);
    }
}

__global__ void k_scatter(const int* __restrict__ src_arr, const int* __restrict__ dst_arr, int E, int N,
                          const int* __restrict__ row_ptr, int* __restrict__ cnt, int* __restrict__ csr_src) {
    int ET = E + N;
    int slice = blockIdx.x >> 3;
    int range = blockIdx.x & 7;
    int rsz = (N + 7) >> 3;
    int lo = range * rsz;
    int hi = lo + rsz; if (hi > N) hi = N;
    int base = slice * SLICE;
    int end = base + SLICE; if (end > ET) end = ET;
    for (int e = base + threadIdx.x; e < end; e += 256) {
        int s, d;
        if (e < E) { s = src_arr[e]; d = dst_arr[e]; }
        else { s = e - E; d = e - E; }
        if (d >= lo && d < hi) {
            int pos = atomicAdd(&cnt[d], 1);
            csr_src[row_ptr[d] + pos] = s;
        }
    }
}

__global__ __launch_bounds__(256) void k_gemm(const float* __restrict__ x,
                                              const float* __restrict__ ue, const float* __restrict__ ie, int NU,
                                              const float* __restrict__ W,
                                              const float* __restrict__ att_s, const float* __restrict__ att_d,
                                              float* __restrict__ h, float* __restrict__ as_, float* __restrict__ ad_,
                                              int N) {
    __shared__ float sW[64 * 64];
    __shared__ float sX[128 * 65];
    __shared__ float sAs[64], sAd[64];
    int t = threadIdx.x;
    int row0 = blockIdx.x * 128;
    {
        const float4* Wv = (const float4*)W;
        float4* sWv = (float4*)sW;
#pragma unroll
        for (int u = 0; u < 4; u++) sWv[t + 256 * u] = Wv[t + 256 * u];
    }
    if (t < 64) { sAs[t] = att_s[t]; sAd[t] = att_d[t]; }
    {
#pragma unroll
        for (int u = 0; u < 8; u++) {
            int idx = t + 256 * u;
            int r = idx >> 4, c4 = idx & 15;
            int grow = row0 + r;
            float4 v = make_float4(0.f, 0.f, 0.f, 0.f);
            if (grow < N) {
                const float* base = x ? (x + (size_t)grow * 64)
                                      : (grow < NU ? ue + (size_t)grow * 64 : ie + (size_t)(grow - NU) * 64);
                v = ((const float4*)base)[c4];
            }
            int cc = c4 * 4;
            sX[r * 65 + cc] = v.x; sX[r * 65 + cc + 1] = v.y; sX[r * 65 + cc + 2] = v.z; sX[r * 65 + cc + 3] = v.w;
        }
    }
    __syncthreads();
    int rl = t >> 2;
    int g = t & 3;
    int c0 = g * 16;
    int rA = rl * 2, rB = rA + 1;
    float accA[16], accB[16];
#pragma unroll
    for (int j = 0; j < 16; j++) { accA[j] = 0.f; accB[j] = 0.f; }
    for (int k = 0; k < 64; k++) {
        float xa = sX[rA * 65 + k];
        float xb = sX[rB * 65 + k];
        const float4* wr = (const float4*)&sW[k * 64 + c0];
        float4 w0 = wr[0], w1 = wr[1], w2 = wr[2], w3 = wr[3];
        accA[0] += xa * w0.x; accA[1] += xa * w0.y; accA[2] += xa * w0.z; accA[3] += xa * w0.w;
        accA[4] += xa * w1.x; accA[5] += xa * w1.y; accA[6] += xa * w1.z; accA[7] += xa * w1.w;
        accA[8] += xa * w2.x; accA[9] += xa * w2.y; accA[10] += xa * w2.z; accA[11] += xa * w2.w;
        accA[12] += xa * w3.x; accA[13] += xa * w3.y; accA[14] += xa * w3.z; accA[15] += xa * w3.w;
        accB[0] += xb * w0.x; accB[1] += xb * w0.y; accB[2] += xb * w0.z; accB[3] += xb * w0.w;
        accB[4] += xb * w1.x; accB[5] += xb * w1.y; accB[6] += xb * w1.z; accB[7] += xb * w1.w;
        accB[8] += xb * w2.x; accB[9] += xb * w2.y; accB[10] += xb * w2.z; accB[11] += xb * w2.w;
        accB[12] += xb * w3.x; accB[13] += xb * w3.y; accB[14] += xb * w3.z; accB[15] += xb * w3.w;
    }
    float sA = 0.f, dA = 0.f, sB = 0.f, dB = 0.f;
#pragma unroll
    for (int j = 0; j < 16; j++) {
        sA += accA[j] * sAs[c0 + j]; dA += accA[j] * sAd[c0 + j];
        sB += accB[j] * sAs[c0 + j]; dB += accB[j] * sAd[c0 + j];
    }
    sA += __shfl_xor(sA, 1); sA += __shfl_xor(sA, 2);
    dA += __shfl_xor(dA, 1); dA += __shfl_xor(dA, 2);
    sB += __shfl_xor(sB, 1); sB += __shfl_xor(sB, 2);
    dB += __shfl_xor(dB, 1); dB += __shfl_xor(dB, 2);
    int rowA = row0 + rA, rowB = row0 + rB;
    if (rowA < N) {
        if (g == 0) { as_[rowA] = sA; ad_[rowA] = dA; }
        float4* hv = (float4*)&h[(size_t)rowA * 64 + c0];
        hv[0] = make_float4(accA[0], accA[1], accA[2], accA[3]);
        hv[1] = make_float4(accA[4], accA[5], accA[6], accA[7]);
        hv[2] = make_float4(accA[8], accA[9], accA[10], accA[11]);
        hv[3] = make_float4(accA[12], accA[13], accA[14], accA[15]);
    }
    if (rowB < N) {
        if (g == 0) { as_[rowB] = sB; ad_[rowB] = dB; }
        float4* hv = (float4*)&h[(size_t)rowB * 64 + c0];
        hv[0] = make_float4(accB[0], accB[1], accB[2], accB[3]);
        hv[1] = make_float4(accB[4], accB[5], accB[6], accB[7]);
        hv[2] = make_float4(accB[8], accB[9], accB[10], accB[11]);
        hv[3] = make_float4(accB[12], accB[13], accB[14], accB[15]);
    }
}

__global__ __launch_bounds__(256) void k_agg(const float* __restrict__ h,
                                             const int* __restrict__ row_ptr, const int* __restrict__ csr_src,
                                             const float* __restrict__ as_, const float* __restrict__ ad_,
                                             const float* __restrict__ bias, float* __restrict__ xout, int N) {
    int wid = threadIdx.x >> 6, lane = threadIdx.x & 63;
    int d = blockIdx.x * 4 + wid;
    if (d >= N) return;
    int s0 = row_ptr[d], s1 = row_ptr[d + 1];
    float adv = ad_[d];
    int j0 = s0 + lane;
    int sv0 = 0; float ev0 = -1e30f;
    if (j0 < s1) {
        sv0 = csr_src[j0];
        float e = as_[sv0] + adv;
        ev0 = (e > 0.f) ? e : 0.2f * e;
    }
    float m = ev0;
    for (int j = j0 + 64; j < s1; j += 64) {
        float e = as_[csr_src[j]] + adv;
        e = (e > 0.f) ? e : 0.2f * e;
        m = fmaxf(m, e);
    }
#pragma unroll
    for (int o = 32; o; o >>= 1) m = fmaxf(m, __shfl_xor(m, o));
    float ex0 = (j0 < s1) ? expf(ev0 - m) : 0.f;
    float sum = ex0;
    for (int j = j0 + 64; j < s1; j += 64) {
        float e = as_[csr_src[j]] + adv;
        e = (e > 0.f) ? e : 0.2f * e;
        sum += expf(e - m);
    }
#pragma unroll
    for (int o = 32; o; o >>= 1) sum += __shfl_xor(sum, o);
    float inv = 1.f / sum;
    ex0 *= inv;
    int sub = lane >> 4;
    int c4 = lane & 15;
    float4 acc = make_float4(0.f, 0.f, 0.f, 0.f);
    for (int cbase = s0; cbase < s1; cbase += 64) {
        int sv; float ex;
        if (cbase == s0) { sv = sv0; ex = ex0; }
        else {
            int jj = cbase + lane;
            sv = 0; ex = 0.f;
            if (jj < s1) {
                sv = csr_src[jj];
                float e = as_[sv] + adv;
                e = (e > 0.f) ? e : 0.2f * e;
                ex = expf(e - m) * inv;
            }
        }
        int cnt2 = s1 - cbase; if (cnt2 > 64) cnt2 = 64;
        for (int q = 0; q < cnt2; q += 4) {
            int il = q + sub;
            float w = __shfl(ex, il);
            int s = __shfl(sv, il);
            const float4 hv = *(const float4*)&h[(size_t)s * 64 + (c4 << 2)];
            acc.x += w * hv.x; acc.y += w * hv.y; acc.z += w * hv.z; acc.w += w * hv.w;
        }
    }
#pragma unroll
    for (int o = 16; o <= 32; o <<= 1) {
        acc.x += __shfl_xor(acc.x, o);
        acc.y += __shfl_xor(acc.y, o);
        acc.z += __shfl_xor(acc.z, o);
        acc.w += __shfl_xor(acc.w, o);
    }
    if (lane < 16) {
        float4 bv = ((const float4*)bias)[c4];
        acc.x += bv.x; acc.y += bv.y; acc.z += bv.z; acc.w += bv.w;
        ((float4*)&xout[(size_t)d * 64])[c4] = acc;
    }
}

__global__ __launch_bounds__(256) void k_pred(const float* __restrict__ x, const int* __restrict__ idx,
                                              int nIdx, int rowOff, const float* __restrict__ W,
                                              const float* __restrict__ bvec, float* __restrict__ out) {
    __shared__ float sWt[64 * 65];
    int t = threadIdx.x;
#pragma unroll
    for (int u = 0; u < 16; u++) {
        int i = u * 256 + t;
        int c = i >> 6, k = i & 63;
        sWt[k * 65 + c] = W[i];
    }
    __syncthreads();
    int wid = t >> 6, lane = t & 63;
    int r = blockIdx.x * 4 + wid;
    if (r >= nIdx) return;
    int node = idx ? (idx[r] + rowOff) : (r + rowOff);
    float xr = x[(size_t)node * 64 + lane];
    float acc = bvec[lane];
    for (int k = 0; k < 64; k++)
        acc += __shfl(xr, k) * sWt[k * 65 + lane];
    out[(size_t)r * 64 + lane] = acc;
}

__global__ void k_gather(const float* __restrict__ x, const int* __restrict__ idx, int nIdx, int rowOff,
                         float* __restrict__ out) {
    int t = blockIdx.x * blockDim.x + threadIdx.x;
    if (t < nIdx * 64) {
        int r = t >> 6, c = t & 63;
        int node = idx[r] + rowOff;
        out[t] = x[(size_t)node * 64 + c];
    }
}

extern "C" void kernel_launch(void* const* d_in, const int* in_sizes, int n_in,
                              void* d_out, int out_size, void* d_ws, size_t ws_size,
                              hipStream_t stream) {
    const int* user = (const int*)d_in[0];
    const int* item = (const int*)d_in[1];
    const int* edge = (const int*)d_in[2];
    const float* user_emb_o = (const float*)d_in[3];
    const float* item_emb_o = (const float*)d_in[4];
    const float* W_o = (const float*)d_in[5];
    const float* att_src_o = (const float*)d_in[6];
    const float* att_dst_o = (const float*)d_in[7];
    const float* bias_o = (const float*)d_in[8];
    const float* user_emb_t = (const float*)d_in[9];
    const float* item_emb_t = (const float*)d_in[10];
    const float* W_t = (const float*)d_in[11];
    const float* att_src_t = (const float*)d_in[12];
    const float* att_dst_t = (const float*)d_in[13];
    const float* bias_t = (const float*)d_in[14];
    const float* pred_W = (const float*)d_in[15];
    const float* pred_b = (const float*)d_in[16];
    float* out = (float*)d_out;

    int E = in_sizes[2] / 2;
    int NU = in_sizes[3] / LAT;
    int NI = in_sizes[4] / LAT;
    int N = NU + NI;
    int ET = E + N;
    int nU = in_sizes[0];
    int nI = in_sizes[1];
    int nSel = nU + nI;
    int rsz = (N + 7) >> 3;

    const int* src_arr = edge;
    const int* dst_arr = edge + E;

    auto al = [](size_t v) { return (v + 255) & ~(size_t)255; };

    // ---- primary layout ----
    char* p = (char*)d_ws;
    float* x_o   = (float*)p;  p += al((size_t)N * LAT * 4);
    float* x_t   = (float*)p;  p += al((size_t)N * LAT * 4);
    float* h2    = (float*)p;  p += al((size_t)N * 2 * LAT * 4);
    float* asv   = (float*)p;  p += al((size_t)N * 8);
    float* adv   = (float*)p;  p += al((size_t)N * 8);
    int* row_ptr = (int*)p;    p += al((size_t)(N + 1) * 4);
    int* cnt     = (int*)p;    size_t cntsz = al((size_t)N * 4); p += cntsz;
    int* gcur    = (int*)p;    p += al(64);
    int* csr_src = (int*)p;    p += al((size_t)ET * 4);
    int* blk     = (int*)p;    p += al(4096);
    float* xsel  = (float*)p;  p += al((size_t)nSel * LAT * 4);
    size_t need_primary = (size_t)(p - (char*)d_ws);

    // buckets alias x_o (unused during CSR build)
    int bcap = ET / 8 + 16384;
    int2* buckets = (int2*)x_o;  // ~22MB <= 38.4MB

    bool primary = ws_size >= need_primary;

    if (primary) {
        int gemmGrid = cdiv(N, 128) * 2;
        int binGrid = 1024;
        // zero cnt + gcur (contiguous)
        hipMemsetAsync(cnt, 0, cntsz + 64, stream);
        // fused: layer-0 gemm (both encoders) + edge binning w/ degree count
        k_l0<<<gemmGrid + binGrid, 256, 0, stream>>>(
                user_emb_o, item_emb_o, user_emb_t, item_emb_t, NU,
                W_o, W_t, att_src_o, att_dst_o, att_src_t, att_dst_t,
                h2, asv, adv, N,
                gemmGrid, binGrid,
                src_arr, dst_arr, E, ET, rsz, bcap,
                buckets, gcur, cnt);
        int NB = cdiv(N, 1024);
        k_scan1<<<NB, 256, 0, stream>>>(cnt, N, row_ptr, blk);
        k_scan2<<<1, 256, 0, stream>>>(blk, NB);
        k_scan3<<<NB, 256, 0, stream>>>(row_ptr, blk, N, ET);
        hipMemsetAsync(cnt, 0, (size_t)N * 4, stream);
        k_binB<<<1024, 256, 0, stream>>>(buckets, bcap, gcur, row_ptr, cnt, csr_src);

        // ---- layers ----
        for (int l = 0; l < 3; l++) {
            if (l > 0) {
                k_gemm2m<<<cdiv(N, 128) * 2, 256, 0, stream>>>(x_o, x_t, NU,
                        W_o + l * 4096, W_t + l * 4096,
                        att_src_o + l * 64, att_dst_o + l * 64,
                        att_src_t + l * 64, att_dst_t + l * 64,
                        h2, asv, adv, N);
            }
            if (l < 2) {
                k_agg2<<<cdiv(N, 4), 256, 0, stream>>>(h2, row_ptr, csr_src,
                        (const float2*)asv, (const float2*)adv,
                        bias_o + l * 64, bias_t + l * 64,
                        x_o, x_t, N,
                        nullptr, nullptr, 0, 0, NU, nullptr, nullptr, nullptr);
            } else {
                k_agg2<<<cdiv(nSel, 4), 256, 0, stream>>>(h2, row_ptr, csr_src,
                        (const float2*)asv, (const float2*)adv,
                        bias_o + l * 64, bias_t + l * 64,
                        nullptr, nullptr, N,
                        user, item, nSel, nU, NU,
                        xsel, out + (size_t)nU * LAT, out + (size_t)3 * nU * LAT);
            }
        }
        k_pred2<<<cdiv(nSel, 4), 256, 0, stream>>>(xsel, nU, nI, pred_W, pred_b,
                                                   out, out + (size_t)2 * nU * LAT);
        return;
    }

    // ---- fallback: sequential encoders ----
    p = (char*)d_ws;
    float* x_cur = (float*)p;  p += al((size_t)N * LAT * 4);
    float* h     = (float*)p;  p += al((size_t)N * LAT * 4);
    float* as_   = (float*)p;  p += al((size_t)N * 4);
    float* ad_   = (float*)p;  p += al((size_t)N * 4);
    row_ptr = (int*)p;         p += al((size_t)(N + 1) * 4);
    cnt     = (int*)p;         p += al((size_t)N * 4);
    csr_src = (int*)p;         p += al((size_t)ET * 4);
    blk     = (int*)p;         p += al(4096);

    hipMemsetAsync(cnt, 0, (size_t)N * 4, stream);
    k_count<<<cdiv(ET, 256), 256, 0, stream>>>(dst_arr, E, N, cnt);
    int NB = cdiv(N, 1024);
    k_scan1<<<NB, 256, 0, stream>>>(cnt, N, row_ptr, blk);
    k_scan2<<<1, 256, 0, stream>>>(blk, NB);
    k_scan3<<<NB, 256, 0, stream>>>(row_ptr, blk, N, ET);
    hipMemsetAsync(cnt, 0, (size_t)N * 4, stream);
    k_scatter<<<cdiv(ET, SLICE) * 8, 256, 0, stream>>>(src_arr, dst_arr, E, N, row_ptr, cnt, csr_src);

    auto run_encoder = [&](const float* ue, const float* ie, const float* Wl,
                           const float* asl, const float* adl, const float* bl) {
        for (int l = 0; l < 3; l++) {
            const float* xin = (l == 0) ? nullptr : x_cur;
            k_gemm<<<cdiv(N, 128), 256, 0, stream>>>(xin, ue, ie, NU, Wl + l * 64 * 64, asl + l * 64,
                                                     adl + l * 64, h, as_, ad_, N);
            k_agg<<<cdiv(N, 4), 256, 0, stream>>>(h, row_ptr, csr_src, as_, ad_, bl + l * 64, x_cur, N);
        }
    };

    run_encoder(user_emb_o, item_emb_o, W_o, att_src_o, att_dst_o, bias_o);
    k_pred<<<cdiv(nU, 4), 256, 0, stream>>>(x_cur, user, nU, 0, pred_W, pred_b, out);
    k_pred<<<cdiv(nI, 4), 256, 0, stream>>>(x_cur, item, nI, NU, pred_W, pred_b, out + (size_t)2 * nU * LAT);

    run_encoder(user_emb_t, item_emb_t, W_t, att_src_t, att_dst_t, bias_t);
    k_gather<<<cdiv(nU * LAT, 256), 256, 0, stream>>>(x_cur, user, nU, 0, out + (size_t)nU * LAT);
    k_gather<<<cdiv(nI * LAT, 256), 256, 0, stream>>>(x_cur, item, nI, NU, out + (size_t)3 * nU * LAT);
}